// Round 6
// baseline (1002.302 us; speedup 1.0000x reference)
//
#include <hip/hip_runtime.h>
#include <hip/hip_bf16.h>

#define B_   128
#define TE_  512
#define TD_  128
#define EH_  512
#define DH_  512
#define KC_  7
#define CC_  105
#define G_   2048   // 4*DH
#define KX_  617    // EH + CC
#define KP_  640    // padded K for gates GEMM

typedef __attribute__((ext_vector_type(8))) short bf16x8;
typedef __attribute__((ext_vector_type(4))) float f32x4;

__device__ __forceinline__ float sigm(float x){ return 1.f/(1.f + __expf(-x)); }
__device__ __forceinline__ float tanhf_fast(float x){
  float e = __expf(2.f*x);
  return 1.f - 2.f/(e + 1.f);
}

// fp32 -> bf16 (RNE)
__device__ __forceinline__ unsigned short f2bf(float f){
  unsigned int u = __float_as_uint(f);
  unsigned int r = (u + 0x7fffu + ((u >> 16) & 1u)) >> 16;
  return (unsigned short)r;
}

__device__ __forceinline__ float dot512f(const float* a, const float* b) {
  const float4* a4 = (const float4*)a; const float4* b4 = (const float4*)b;
  float acc = 0.f;
  #pragma unroll 8
  for (int q = 0; q < 128; ++q) {
    float4 x = a4[q], y = b4[q];
    acc += x.x*y.x + x.y*y.y + x.z*y.z + x.w*y.w;
  }
  return acc;
}

// ---------------- workspace layout (bytes) ----------------
static const size_t OFF_PHI  = 0;                                         // 1 MB
static const size_t OFF_WA   = OFF_PHI  + (size_t)TE_*EH_*4;              // 64 KB
static const size_t OFF_HPRE = OFF_WA   + (size_t)B_*TD_*4;               // 1 MB
static const size_t OFF_EP   = OFF_HPRE + (size_t)B_*G_*4;                // 4 KB
static const size_t OFF_CP   = OFF_EP   + 4096;                           // 53.8 KB
static const size_t OFF_E2   = ((OFF_CP + (size_t)B_*CC_*4 + 255)/256)*256; // 33.5 MB fp32 [b][i][t]; X bf16 aliases
static const size_t OFF_P    = OFF_E2 + (size_t)B_*TD_*TE_*4;             // 16.7 MB bf16 [b][i][t]
static const size_t OFF_LT   = OFF_P  + (size_t)B_*TD_*TE_*2;             // 67 MB bf16
static const size_t OFF_WR   = OFF_LT + (size_t)B_*TE_*EH_*2;             // 2.6 MB bf16
// scratch aliases inside the P region (dead before k_softmaxP writes P):
static const size_t OFF_PT   = OFF_P;                                     // 1 MB fp32 phi_w^T
static const size_t OFF_UB   = OFF_P + (size_t)TE_*EH_*4;                 // 0.5 MB bf16 Ua_w
static const size_t OFF_SUM  = OFF_UB + (size_t)TE_*EH_*2;                // 16 KB scan sums

// ---- phi_w [e][t] -> phiT [t][e] ----
__global__ __launch_bounds__(256) void k_trw(const float* __restrict__ phi_w,
                                             float* __restrict__ phiT) {
  int e0 = blockIdx.x * 64, t0 = blockIdx.y * 64;
  __shared__ float tile[64][65];
  int tid = threadIdx.x;
  int r = tid >> 2, c16 = (tid & 3) * 16;
  const float4* src = (const float4*)(phi_w + (size_t)(e0 + r)*TE_ + t0 + c16);
  float4 v0 = src[0], v1 = src[1], v2 = src[2], v3 = src[3];
  *(float4*)&tile[r][c16]    = v0;
  *(float4*)&tile[r][c16+4]  = v1;
  *(float4*)&tile[r][c16+8]  = v2;
  *(float4*)&tile[r][c16+12] = v3;
  __syncthreads();
  float o[16];
  #pragma unroll
  for (int j = 0; j < 16; ++j) o[j] = tile[c16+j][r];
  float* dst = phiT + (size_t)(t0 + r)*EH_ + e0 + c16;
  *(float4*)dst      = *(float4*)&o[0];
  *(float4*)(dst+4)  = *(float4*)&o[4];
  *(float4*)(dst+8)  = *(float4*)&o[8];
  *(float4*)(dst+12) = *(float4*)&o[12];
}

// ---- split exclusive scan over t: phase A local prefix + chunk sums ----
__global__ void k_phiA(const float* __restrict__ phiT, float* __restrict__ phi,
                       float* __restrict__ sums) {
  int e = blockIdx.x * 256 + threadIdx.x;   // 512
  int z = blockIdx.y;                        // 8 chunks of 64 t
  float acc = 0.f;
  for (int t = z*64; t < z*64 + 64; ++t) {
    phi[(size_t)t*EH_ + e] = acc;
    acc += phiT[(size_t)t*EH_ + e];
  }
  sums[z*EH_ + e] = acc;
}
// ---- phase B: add chunk offsets + phi_b ----
__global__ void k_phiB(const float* __restrict__ sums, const float* __restrict__ phi_b,
                       float* __restrict__ phi) {
  int e = blockIdx.x * 256 + threadIdx.x;
  int z = blockIdx.y;
  float off = phi_b[e];
  for (int zz = 0; zz < z; ++zz) off += sums[zz*EH_ + e];
  for (int t = z*64; t < z*64 + 64; ++t)
    phi[(size_t)t*EH_ + e] += off;
}

__global__ void k_wa(const float* __restrict__ s_i, const float* __restrict__ Wa_w,
                     const float* __restrict__ Wa_b, const float* __restrict__ va_w,
                     float* __restrict__ wa) {
  int id = blockIdx.x * blockDim.x + threadIdx.x;  // 16384
  int b = id >> 7, d = id & 127;
  float acc = Wa_b[d] + dot512f(s_i + (size_t)b*DH_, Wa_w + (size_t)d*DH_);
  wa[id] = tanhf_fast(acc) * va_w[d];
}

__global__ void k_hpre(const float* __restrict__ s_i, const float* __restrict__ Whh,
                       const float* __restrict__ bih, const float* __restrict__ bhh,
                       float* __restrict__ hpre) {
  int id = blockIdx.x * blockDim.x + threadIdx.x; // 262144
  int b = id >> 11, g = id & 2047;
  hpre[id] = bih[g] + bhh[g] + dot512f(s_i + (size_t)b*DH_, Whh + (size_t)g*DH_);
}

// ---- ep: one wave per (b,k) ----
__global__ __launch_bounds__(256) void k_ep(const float* __restrict__ CNNs,
                                            const float* __restrict__ wij_w,
                                            const float* __restrict__ wij_b,
                                            const float* __restrict__ s_i,
                                            float* __restrict__ ep) {
  int gw = blockIdx.x * 4 + (threadIdx.x >> 6);
  int lane = threadIdx.x & 63;
  if (gw >= B_*KC_) return;
  int b = gw / KC_, k = gw % KC_;
  const float* cr = CNNs + (size_t)(b*KC_ + k)*CC_;
  const float* wr = wij_w + (size_t)k*KX_;
  float acc = 0.f;
  for (int c = lane; c < CC_; c += 64) acc += cr[c] * wr[c];
  const float* sr = s_i + (size_t)b*DH_;
  const float* wsr = wr + CC_;
  #pragma unroll
  for (int j = 0; j < 8; ++j) { int h = lane + j*64; acc += sr[h] * wsr[h]; }
  #pragma unroll
  for (int m = 32; m; m >>= 1) acc += __shfl_xor(acc, m, 64);
  if (lane == 0) ep[gw] = tanhf_fast(acc + wij_b[k]);
}

__global__ void k_cnn_fin(const float* __restrict__ ep, const float* __restrict__ CNNs,
                          float* __restrict__ cp) {
  __shared__ float red[1024];
  __shared__ float apl[B_*KC_];
  int tid = threadIdx.x;
  red[tid] = (tid < B_*KC_) ? ep[tid] : 0.f;
  __syncthreads();
  for (int off = 512; off > 0; off >>= 1) {
    if (tid < off) red[tid] += red[tid + off];
    __syncthreads();
  }
  float S = red[0];
  if (tid < B_*KC_) apl[tid] = __expf(ep[tid]) / S;   // ref: exp(ep)/sum(ep), GLOBAL sum
  __syncthreads();
  for (int idx = tid; idx < B_*CC_; idx += blockDim.x) {
    int b = idx / CC_, c = idx % CC_;
    float acc = 0.f;
    #pragma unroll
    for (int k = 0; k < KC_; ++k)
      acc += apl[b*KC_ + k] * CNNs[(size_t)(b*KC_ + k)*CC_ + c];
    cp[idx] = acc;
  }
}

// ---- Wih fp32 -> bf16 [2048][640], rows reordered nr = dh*4+gate ----
__global__ void k_cvtW(const float* __restrict__ Wih, unsigned short* __restrict__ Wr) {
  int id = blockIdx.x * 256 + threadIdx.x;    // 2048*80
  int nr = id / 80, c8 = (id % 80) * 8;
  int gate = nr & 3, dh = nr >> 2;
  const float* src = Wih + (size_t)(gate*DH_ + dh)*KX_;
  unsigned short o[8];
  #pragma unroll
  for (int j = 0; j < 8; ++j) {
    int col = c8 + j;
    o[j] = (col < KX_) ? f2bf(src[col]) : 0;
  }
  *(uint4*)(Wr + (size_t)nr*KP_ + c8) = *(uint4*)o;
}

// ---- Ua_w fp32 -> bf16 ----
__global__ void k_cvtU(const float* __restrict__ Ua_w, unsigned short* __restrict__ UB) {
  int id = blockIdx.x * 256 + threadIdx.x;    // 32768
  int off = id * 8;
  float4 a = *(const float4*)(Ua_w + off);
  float4 b = *(const float4*)(Ua_w + off + 4);
  unsigned short o[8] = {f2bf(a.x), f2bf(a.y), f2bf(a.z), f2bf(a.w),
                         f2bf(b.x), f2bf(b.y), f2bf(b.z), f2bf(b.w)};
  *(uint4*)(UB + off) = *(uint4*)o;
}

// ---- LSTM [b][t][e] fp32 -> LT [b][e][t] bf16 ----
__global__ __launch_bounds__(256) void k_ltrans(const float* __restrict__ LSTM,
                                                unsigned short* __restrict__ LT) {
  int e0 = blockIdx.x * 64, t0 = blockIdx.y * 64, b = blockIdx.z;
  __shared__ float tile[64][65];
  int tid = threadIdx.x;
  int tt = tid >> 2, c16 = (tid & 3) * 16;
  const float4* src = (const float4*)(LSTM + ((size_t)b*TE_ + t0 + tt)*EH_ + e0 + c16);
  float4 v0 = src[0], v1 = src[1], v2 = src[2], v3 = src[3];
  *(float4*)&tile[tt][c16]    = v0;
  *(float4*)&tile[tt][c16+4]  = v1;
  *(float4*)&tile[tt][c16+8]  = v2;
  *(float4*)&tile[tt][c16+12] = v3;
  __syncthreads();
  int e = tid >> 2, t16 = (tid & 3) * 16;
  unsigned short o[16];
  #pragma unroll
  for (int j = 0; j < 16; ++j) o[j] = f2bf(tile[t16+j][e]);
  unsigned short* dst = LT + ((size_t)b*EH_ + e0 + e)*TE_ + t0 + t16;
  *(uint4*)dst     = *(uint4*)&o[0];
  *(uint4*)(dst+8) = *(uint4*)&o[8];
}

// ---------- phase 1: banded logits band-GEMM; coalesced E2[b][i][t] output ----------
#define LDA_  40
#define LDB_  40
__global__ __launch_bounds__(256) void k_bandmm(const float* __restrict__ LSTM,
                                                const float* __restrict__ phi,
                                                const unsigned short* __restrict__ UB,
                                                const float* __restrict__ Ua_b,
                                                const float* __restrict__ va_w,
                                                const float* __restrict__ va_b,
                                                const float* __restrict__ wa,
                                                float* __restrict__ E2) {
  int t0 = blockIdx.x * 64;      // 8 tiles
  int b  = blockIdx.y;           // 128
  int s_base = 321 - t0;
  __shared__ __align__(16) char smem[128*68*4];   // 34.8 KB; sA/sB then reused as tile
  short* sA = (short*)smem;                        // 64*40*2  = 5120 B
  short* sB = (short*)(smem + 64*LDA_*2);          // 192*40*2 = 15360 B
  float (*tile)[68] = (float (*)[68])smem;         // 128 x 68 fp32
  int tid = threadIdx.x;
  int wave = tid >> 6, lane = tid & 63;
  int quad = lane >> 4, l16 = lane & 15;

  f32x4 acc[4][3];
  #pragma unroll
  for (int m = 0; m < 4; ++m)
    #pragma unroll
    for (int n = 0; n < 3; ++n)
      acc[m][n] = (f32x4){0.f, 0.f, 0.f, 0.f};

  int arow = tid >> 2;
  int ach  = (tid & 3) * 8;
  int aq   = ach >> 2;

  const float4* baseL = (const float4*)(LSTM + ((size_t)b*TE_ + t0 + arow)*EH_);
  const float4* baseP = (const float4*)(phi + (size_t)(t0 + arow)*EH_);
  const uint4* baseU[3];
  int brow[3], bch[3];
  #pragma unroll
  for (int c = 0; c < 3; ++c) {
    int idx = c*256 + tid;
    brow[c] = idx >> 2;
    bch[c]  = (idx & 3) * 8;
    int s = s_base + brow[c];
    int sc = s < 0 ? 0 : (s > 511 ? 511 : s);
    baseU[c] = (const uint4*)(UB + (size_t)sc*EH_ + bch[c]);
  }

  float4 l0 = baseL[aq], l1 = baseL[aq+1], p0 = baseP[aq], p1 = baseP[aq+1];
  uint4 u[3];
  #pragma unroll
  for (int c = 0; c < 3; ++c) u[c] = baseU[c][0];

  for (int k0 = 0; k0 < EH_; k0 += 32) {
    unsigned short at[8];
    at[0]=f2bf(l0.x*p0.x); at[1]=f2bf(l0.y*p0.y); at[2]=f2bf(l0.z*p0.z); at[3]=f2bf(l0.w*p0.w);
    at[4]=f2bf(l1.x*p1.x); at[5]=f2bf(l1.y*p1.y); at[6]=f2bf(l1.z*p1.z); at[7]=f2bf(l1.w*p1.w);
    uint4 bt[3];
    #pragma unroll
    for (int c = 0; c < 3; ++c) bt[c] = u[c];
    if (k0 + 32 < EH_) {
      int q = (k0 + 32) >> 2;
      l0 = baseL[q+aq]; l1 = baseL[q+aq+1]; p0 = baseP[q+aq]; p1 = baseP[q+aq+1];
      int qu = (k0 + 32) >> 3;
      #pragma unroll
      for (int c = 0; c < 3; ++c) u[c] = baseU[c][qu];
    }
    __syncthreads();
    *(uint4*)&sA[arow*LDA_ + ach] = *(uint4*)at;
    #pragma unroll
    for (int c = 0; c < 3; ++c)
      *(uint4*)&sB[brow[c]*LDB_ + bch[c]] = bt[c];
    __syncthreads();
    bf16x8 bfr[3];
    #pragma unroll
    for (int n = 0; n < 3; ++n)
      bfr[n] = *(const bf16x8*)&sB[(l16 + (wave*3 + n)*16)*LDB_ + quad*8];
    #pragma unroll
    for (int m = 0; m < 4; ++m) {
      bf16x8 af = *(const bf16x8*)&sA[(l16 + m*16)*LDA_ + quad*8];
      #pragma unroll
      for (int n = 0; n < 3; ++n)
        acc[m][n] = __builtin_amdgcn_mfma_f32_16x16x32_bf16(af, bfr[n], acc[m][n], 0, 0, 0);
    }
  }

  __syncthreads();   // sA/sB dead; reuse as (i,t) tile
  float vb = va_b[0];
  #pragma unroll
  for (int n = 0; n < 3; ++n) {
    int s = s_base + wave*48 + n*16 + l16;
    float ub = (s >= 0 && s < TE_) ? Ua_b[s] : 0.f;
    float vw = (s >= 0 && s < TE_) ? va_w[TD_ + s] : 0.f;
    #pragma unroll
    for (int m = 0; m < 4; ++m) {
      #pragma unroll
      for (int r = 0; r < 4; ++r) {
        int tl = m*16 + quad*4 + r;
        int i = s + t0 + tl - 384;
        if (i >= 0 && i < TD_) {
          float val;
          if (s >= 0) val = tanhf_fast(acc[m][n][r] + ub) * vw + vb;
          else        val = wa[b*TD_ + s + 128] + vb;
          tile[i][tl] = val;
        }
      }
    }
  }
  __syncthreads();
  // coalesced store: 16 lanes cover one row's 64 floats
  int g = tid >> 4, l = tid & 15;
  #pragma unroll
  for (int p = 0; p < 8; ++p) {
    int i = p*16 + g;
    *(float4*)(E2 + ((size_t)b*TD_ + i)*TE_ + t0 + l*4) = *(const float4*)&tile[i][l*4];
  }
}

// ---- softmax over t per (b,i) row + bf16 P, one wave per row ----
__global__ __launch_bounds__(256) void k_softmaxP(const float* __restrict__ E2,
                                                  unsigned short* __restrict__ P) {
  int r = blockIdx.x * 4 + (threadIdx.x >> 6);   // 16384 rows
  int lane = threadIdx.x & 63;
  const float4* src = (const float4*)(E2 + (size_t)r*TE_) + lane*2;
  float4 x0 = src[0], x1 = src[1];
  float m = fmaxf(fmaxf(fmaxf(x0.x,x0.y),fmaxf(x0.z,x0.w)),
                  fmaxf(fmaxf(x1.x,x1.y),fmaxf(x1.z,x1.w)));
  #pragma unroll
  for (int d = 32; d; d >>= 1) m = fmaxf(m, __shfl_xor(m, d, 64));
  float e0 = __expf(x0.x - m), e1 = __expf(x0.y - m), e2 = __expf(x0.z - m), e3 = __expf(x0.w - m);
  float e4 = __expf(x1.x - m), e5 = __expf(x1.y - m), e6 = __expf(x1.z - m), e7 = __expf(x1.w - m);
  float s = e0+e1+e2+e3+e4+e5+e6+e7;
  #pragma unroll
  for (int d = 32; d; d >>= 1) s += __shfl_xor(s, d, 64);
  float inv = 1.f / s;
  unsigned short o[8] = {f2bf(e0*inv), f2bf(e1*inv), f2bf(e2*inv), f2bf(e3*inv),
                         f2bf(e4*inv), f2bf(e5*inv), f2bf(e6*inv), f2bf(e7*inv)};
  *(uint4*)(P + (size_t)r*TE_ + lane*8) = *(uint4*)o;
}

// ---- fill X[:,512:640] from cp (bf16), zero pad ----
__global__ void k_cp_fill(const float* __restrict__ cp, unsigned short* __restrict__ X) {
  int id = blockIdx.x * 256 + threadIdx.x;  // 16384*16
  int m = id >> 4, c8 = (id & 15) * 8;
  int b = m >> 7;
  unsigned short o[8];
  #pragma unroll
  for (int j = 0; j < 8; ++j) {
    int c = c8 + j;
    o[j] = (c < CC_) ? f2bf(cp[b*CC_ + c]) : 0;
  }
  *(uint4*)(X + (size_t)m*KP_ + EH_ + c8) = *(uint4*)o;
}

// ------ phase 3 (MFMA, BK=64): X[b*128+i][e] = sum_t P[b][i][t]*LT[b][e][t] ------
#define G_LD 72
__global__ __launch_bounds__(256) void k_ci_mm(const unsigned short* __restrict__ P,
                                               const unsigned short* __restrict__ LT,
                                               unsigned short* __restrict__ X) {
  int b = blockIdx.x, e0 = blockIdx.y * 128;
  __shared__ short sA[128 * G_LD];
  __shared__ short sB[128 * G_LD];
  int tid = threadIdx.x;
  int wave = tid >> 6, lane = tid & 63, quad = lane >> 4, l16 = lane & 15;
  int wm = wave >> 1, wn = wave & 1;
  int row = tid >> 1, ho = (tid & 1) * 32;

  const unsigned short* pa = P + ((size_t)b*TD_ + row)*TE_ + ho;
  const unsigned short* pb = LT + ((size_t)b*EH_ + e0 + row)*TE_ + ho;

  f32x4 acc[4][4];
  #pragma unroll
  for (int m = 0; m < 4; ++m)
    #pragma unroll
    for (int n = 0; n < 4; ++n)
      acc[m][n] = (f32x4){0.f, 0.f, 0.f, 0.f};

  uint4 a[4], bb[4];
  #pragma unroll
  for (int j = 0; j < 4; ++j) { a[j] = *(const uint4*)(pa + j*8); bb[j] = *(const uint4*)(pb + j*8); }

  for (int k0 = 0; k0 < TE_; k0 += 64) {
    uint4 na[4], nb[4];
    if (k0 + 64 < TE_) {
      #pragma unroll
      for (int j = 0; j < 4; ++j) {
        na[j] = *(const uint4*)(pa + k0 + 64 + j*8);
        nb[j] = *(const uint4*)(pb + k0 + 64 + j*8);
      }
    }
    __syncthreads();
    #pragma unroll
    for (int j = 0; j < 4; ++j) {
      *(uint4*)&sA[row*G_LD + ho + j*8] = a[j];
      *(uint4*)&sB[row*G_LD + ho + j*8] = bb[j];
    }
    __syncthreads();
    #pragma unroll
    for (int ks = 0; ks < 2; ++ks) {
      bf16x8 bfr[4];
      #pragma unroll
      for (int n = 0; n < 4; ++n)
        bfr[n] = *(const bf16x8*)&sB[(wn*64 + n*16 + l16)*G_LD + ks*32 + quad*8];
      #pragma unroll
      for (int m = 0; m < 4; ++m) {
        bf16x8 af = *(const bf16x8*)&sA[(wm*64 + m*16 + l16)*G_LD + ks*32 + quad*8];
        #pragma unroll
        for (int n = 0; n < 4; ++n)
          acc[m][n] = __builtin_amdgcn_mfma_f32_16x16x32_bf16(af, bfr[n], acc[m][n], 0, 0, 0);
      }
    }
    #pragma unroll
    for (int j = 0; j < 4; ++j) { a[j] = na[j]; bb[j] = nb[j]; }
  }

  #pragma unroll
  for (int m = 0; m < 4; ++m) {
    int i = wm*64 + m*16 + quad*4;
    #pragma unroll
    for (int n = 0; n < 4; ++n) {
      int e = e0 + wn*64 + n*16 + l16;
      unsigned short* xp = X + ((size_t)b*TD_ + i)*KP_ + e;
      #pragma unroll
      for (int r = 0; r < 4; ++r)
        xp[(size_t)r*KP_] = f2bf(acc[m][n][r]);
    }
  }
}

// -- phase 4 (MFMA, BK=64): gates = X @ Wr^T + fused LSTM cell --
__global__ __launch_bounds__(256) void k_gates_mm(const unsigned short* __restrict__ Wr,
                                                  const unsigned short* __restrict__ X,
                                                  const float* __restrict__ hpre,
                                                  const float* __restrict__ m_i,
                                                  float* __restrict__ out) {
  int g0 = blockIdx.x * 128;
  int mi0 = blockIdx.y * 128;
  __shared__ short sA[128 * G_LD];
  __shared__ short sB[128 * G_LD];
  int tid = threadIdx.x;
  int wave = tid >> 6, lane = tid & 63, quad = lane >> 4, l16 = lane & 15;
  int wg = wave >> 1, wmi = wave & 1;
  int row = tid >> 1, ho = (tid & 1) * 32;

  const unsigned short* pa = Wr + (size_t)(g0 + row)*KP_ + ho;
  const unsigned short* pb = X + (size_t)(mi0 + row)*KP_ + ho;

  f32x4 acc[4][4];
  #pragma unroll
  for (int m = 0; m < 4; ++m)
    #pragma unroll
    for (int n = 0; n < 4; ++n)
      acc[m][n] = (f32x4){0.f, 0.f, 0.f, 0.f};

  uint4 a[4], bb[4];
  #pragma unroll
  for (int j = 0; j < 4; ++j) { a[j] = *(const uint4*)(pa + j*8); bb[j] = *(const uint4*)(pb + j*8); }

  for (int k0 = 0; k0 < KP_; k0 += 64) {
    uint4 na[4], nb[4];
    if (k0 + 64 < KP_) {
      #pragma unroll
      for (int j = 0; j < 4; ++j) {
        na[j] = *(const uint4*)(pa + k0 + 64 + j*8);
        nb[j] = *(const uint4*)(pb + k0 + 64 + j*8);
      }
    }
    __syncthreads();
    #pragma unroll
    for (int j = 0; j < 4; ++j) {
      *(uint4*)&sA[row*G_LD + ho + j*8] = a[j];
      *(uint4*)&sB[row*G_LD + ho + j*8] = bb[j];
    }
    __syncthreads();
    #pragma unroll
    for (int ks = 0; ks < 2; ++ks) {
      bf16x8 bfr[4];
      #pragma unroll
      for (int n = 0; n < 4; ++n)
        bfr[n] = *(const bf16x8*)&sB[(wmi*64 + n*16 + l16)*G_LD + ks*32 + quad*8];
      #pragma unroll
      for (int m = 0; m < 4; ++m) {
        bf16x8 af = *(const bf16x8*)&sA[(wg*64 + m*16 + l16)*G_LD + ks*32 + quad*8];
        #pragma unroll
        for (int n = 0; n < 4; ++n)
          acc[m][n] = __builtin_amdgcn_mfma_f32_16x16x32_bf16(af, bfr[n], acc[m][n], 0, 0, 0);
      }
    }
    #pragma unroll
    for (int j = 0; j < 4; ++j) { a[j] = na[j]; bb[j] = nb[j]; }
  }

  int bbk = mi0 >> 7;
  const float* hp = hpre + (size_t)bbk*G_;
  #pragma unroll
  for (int m = 0; m < 4; ++m) {
    int dh = (g0 >> 2) + wg*16 + m*4 + quad;
    float h0 = hp[dh], h1 = hp[DH_ + dh], h2 = hp[2*DH_ + dh], h3 = hp[3*DH_ + dh];
    float miv = m_i[(size_t)bbk*DH_ + dh];
    #pragma unroll
    for (int n = 0; n < 4; ++n) {
      int mi = mi0 + wmi*64 + n*16 + l16;
      float ig = acc[m][n][0] + h0;
      float fg = acc[m][n][1] + h1;
      float gg = acc[m][n][2] + h2;
      float og = acc[m][n][3] + h3;
      float c  = sigm(fg)*miv + sigm(ig)*tanhf_fast(gg);
      float h  = sigm(og)*tanhf_fast(c);
      out[(size_t)mi*DH_ + dh] = h;
    }
  }
}

extern "C" void kernel_launch(void* const* d_in, const int* in_sizes, int n_in,
                              void* d_out, int out_size, void* d_ws, size_t ws_size,
                              hipStream_t stream) {
  (void)in_sizes; (void)n_in; (void)out_size; (void)ws_size;
  const float* LSTM  = (const float*)d_in[0];
  const float* CNNs  = (const float*)d_in[1];
  const float* Wa_w  = (const float*)d_in[2];
  const float* Wa_b  = (const float*)d_in[3];
  const float* Ua_w  = (const float*)d_in[4];
  const float* Ua_b  = (const float*)d_in[5];
  const float* va_w  = (const float*)d_in[6];
  const float* va_b  = (const float*)d_in[7];
  const float* phi_w = (const float*)d_in[8];
  const float* phi_b = (const float*)d_in[9];
  const float* Wih   = (const float*)d_in[10];
  const float* Whh   = (const float*)d_in[11];
  const float* bih   = (const float*)d_in[12];
  const float* bhh   = (const float*)d_in[13];
  const float* wij_w = (const float*)d_in[14];
  const float* wij_b = (const float*)d_in[15];
  const float* s_i   = (const float*)d_in[16];
  const float* m_i   = (const float*)d_in[17];
  float* out = (float*)d_out;
  char* ws = (char*)d_ws;

  float* phi  = (float*)(ws + OFF_PHI);
  float* wa   = (float*)(ws + OFF_WA);
  float* hpre = (float*)(ws + OFF_HPRE);
  float* ep   = (float*)(ws + OFF_EP);
  float* cp   = (float*)(ws + OFF_CP);
  float* E2   = (float*)(ws + OFF_E2);
  unsigned short* X  = (unsigned short*)(ws + OFF_E2);   // aliases E2 (dead after softmaxP)
  unsigned short* P  = (unsigned short*)(ws + OFF_P);
  unsigned short* LT = (unsigned short*)(ws + OFF_LT);
  unsigned short* Wr = (unsigned short*)(ws + OFF_WR);
  float* phiT        = (float*)(ws + OFF_PT);            // aliases P region (pre-softmaxP)
  unsigned short* UB = (unsigned short*)(ws + OFF_UB);   // aliases P region
  float* sums        = (float*)(ws + OFF_SUM);           // aliases P region

  k_trw     <<<dim3(8,8),      dim3(256),  0, stream>>>(phi_w, phiT);
  k_phiA    <<<dim3(2,8),      dim3(256),  0, stream>>>(phiT, phi, sums);
  k_phiB    <<<dim3(2,8),      dim3(256),  0, stream>>>(sums, phi_b, phi);
  k_wa      <<<dim3(64),       dim3(256),  0, stream>>>(s_i, Wa_w, Wa_b, va_w, wa);
  k_hpre    <<<dim3(1024),     dim3(256),  0, stream>>>(s_i, Whh, bih, bhh, hpre);
  k_ep      <<<dim3(224),      dim3(256),  0, stream>>>(CNNs, wij_w, wij_b, s_i, ep);
  k_cnn_fin <<<dim3(1),        dim3(1024), 0, stream>>>(ep, CNNs, cp);
  k_cvtW    <<<dim3(640),      dim3(256),  0, stream>>>(Wih, Wr);
  k_cvtU    <<<dim3(128),      dim3(256),  0, stream>>>(Ua_w, UB);
  k_ltrans  <<<dim3(8,8,128),  dim3(256),  0, stream>>>(LSTM, LT);
  k_bandmm  <<<dim3(8,128),    dim3(256),  0, stream>>>(LSTM, phi, UB, Ua_b, va_w, va_b, wa, E2);
  k_softmaxP<<<dim3(4096),     dim3(256),  0, stream>>>(E2, P);
  k_cp_fill <<<dim3(1024),     dim3(256),  0, stream>>>(cp, X);
  k_ci_mm   <<<dim3(128,4),    dim3(256),  0, stream>>>(P, LT, X);
  k_gates_mm<<<dim3(16,128),   dim3(256),  0, stream>>>(Wr, X, hpre, m_i, out);
}

// Round 7
// 575.710 us; speedup vs baseline: 1.7410x; 1.7410x over previous
//
#include <hip/hip_runtime.h>
#include <hip/hip_bf16.h>

#define B_   128
#define TE_  512
#define TD_  128
#define EH_  512
#define DH_  512
#define KC_  7
#define CC_  105
#define G_   2048   // 4*DH
#define KX_  617    // EH + CC
#define KP_  640    // padded K for gates GEMM

typedef __attribute__((ext_vector_type(8))) short bf16x8;
typedef __attribute__((ext_vector_type(4))) float f32x4;

__device__ __forceinline__ float sigm(float x){ return 1.f/(1.f + __expf(-x)); }
__device__ __forceinline__ float tanhf_fast(float x){
  float e = __expf(2.f*x);
  return 1.f - 2.f/(e + 1.f);
}

// fp32 -> bf16 (RNE)
__device__ __forceinline__ unsigned short f2bf(float f){
  unsigned int u = __float_as_uint(f);
  unsigned int r = (u + 0x7fffu + ((u >> 16) & 1u)) >> 16;
  return (unsigned short)r;
}

__device__ __forceinline__ float dot512f(const float* a, const float* b) {
  const float4* a4 = (const float4*)a; const float4* b4 = (const float4*)b;
  float acc = 0.f;
  #pragma unroll 8
  for (int q = 0; q < 128; ++q) {
    float4 x = a4[q], y = b4[q];
    acc += x.x*y.x + x.y*y.y + x.z*y.z + x.w*y.w;
  }
  return acc;
}

// ---------------- workspace layout (bytes) ----------------
static const size_t OFF_PHI  = 0;                                         // 1 MB
static const size_t OFF_WA   = OFF_PHI  + (size_t)TE_*EH_*4;              // 64 KB
static const size_t OFF_HPRE = OFF_WA   + (size_t)B_*TD_*4;               // 1 MB
static const size_t OFF_EP   = OFF_HPRE + (size_t)B_*G_*4;                // 4 KB
static const size_t OFF_CP   = OFF_EP   + 4096;                           // 53.8 KB
static const size_t OFF_ET   = ((OFF_CP + (size_t)B_*CC_*4 + 255)/256)*256; // 33.5 MB fp32 [b][t][i]; X bf16 aliases
static const size_t OFF_STAT = OFF_ET + (size_t)B_*TE_*TD_*4;             // 128 KB
static const size_t OFF_P    = ((OFF_STAT + (size_t)2*B_*TD_*4 + 255)/256)*256; // 16.7 MB bf16
static const size_t OFF_LT   = OFF_P  + (size_t)B_*TD_*TE_*2;             // 67 MB bf16
static const size_t OFF_WR   = OFF_LT + (size_t)B_*TE_*EH_*2;             // 2.6 MB bf16
// scratch aliases inside P region (P written later by k_trP):
static const size_t OFF_PT   = OFF_P;                                     // 1 MB fp32 phi_w^T
static const size_t OFF_SUM  = OFF_PT + (size_t)TE_*EH_*4;                // 16 KB scan sums

// ---- phi_w [e][t] -> phiT [t][e] ----
__global__ __launch_bounds__(256) void k_trw(const float* __restrict__ phi_w,
                                             float* __restrict__ phiT) {
  int e0 = blockIdx.x * 64, t0 = blockIdx.y * 64;
  __shared__ float tile[64][65];
  int tid = threadIdx.x;
  int r = tid >> 2, c16 = (tid & 3) * 16;
  const float4* src = (const float4*)(phi_w + (size_t)(e0 + r)*TE_ + t0 + c16);
  float4 v0 = src[0], v1 = src[1], v2 = src[2], v3 = src[3];
  *(float4*)&tile[r][c16]    = v0;
  *(float4*)&tile[r][c16+4]  = v1;
  *(float4*)&tile[r][c16+8]  = v2;
  *(float4*)&tile[r][c16+12] = v3;
  __syncthreads();
  float o[16];
  #pragma unroll
  for (int j = 0; j < 16; ++j) o[j] = tile[c16+j][r];
  float* dst = phiT + (size_t)(t0 + r)*EH_ + e0 + c16;
  *(float4*)dst      = *(float4*)&o[0];
  *(float4*)(dst+4)  = *(float4*)&o[4];
  *(float4*)(dst+8)  = *(float4*)&o[8];
  *(float4*)(dst+12) = *(float4*)&o[12];
}

// ---- split exclusive scan over t ----
__global__ void k_phiA(const float* __restrict__ phiT, float* __restrict__ phi,
                       float* __restrict__ sums) {
  int e = blockIdx.x * 256 + threadIdx.x;   // 512
  int z = blockIdx.y;                        // 8 chunks of 64 t
  float acc = 0.f;
  for (int t = z*64; t < z*64 + 64; ++t) {
    phi[(size_t)t*EH_ + e] = acc;
    acc += phiT[(size_t)t*EH_ + e];
  }
  sums[z*EH_ + e] = acc;
}
__global__ void k_phiB(const float* __restrict__ sums, const float* __restrict__ phi_b,
                       float* __restrict__ phi) {
  int e = blockIdx.x * 256 + threadIdx.x;
  int z = blockIdx.y;
  float off = phi_b[e];
  for (int zz = 0; zz < z; ++zz) off += sums[zz*EH_ + e];
  for (int t = z*64; t < z*64 + 64; ++t)
    phi[(size_t)t*EH_ + e] += off;
}

__global__ void k_wa(const float* __restrict__ s_i, const float* __restrict__ Wa_w,
                     const float* __restrict__ Wa_b, const float* __restrict__ va_w,
                     float* __restrict__ wa) {
  int id = blockIdx.x * blockDim.x + threadIdx.x;  // 16384
  int b = id >> 7, d = id & 127;
  float acc = Wa_b[d] + dot512f(s_i + (size_t)b*DH_, Wa_w + (size_t)d*DH_);
  wa[id] = tanhf_fast(acc) * va_w[d];
}

__global__ void k_hpre(const float* __restrict__ s_i, const float* __restrict__ Whh,
                       const float* __restrict__ bih, const float* __restrict__ bhh,
                       float* __restrict__ hpre) {
  int id = blockIdx.x * blockDim.x + threadIdx.x; // 262144
  int b = id >> 11, g = id & 2047;
  hpre[id] = bih[g] + bhh[g] + dot512f(s_i + (size_t)b*DH_, Whh + (size_t)g*DH_);
}

// ---- ep: one wave per (b,k) ----
__global__ __launch_bounds__(256) void k_ep(const float* __restrict__ CNNs,
                                            const float* __restrict__ wij_w,
                                            const float* __restrict__ wij_b,
                                            const float* __restrict__ s_i,
                                            float* __restrict__ ep) {
  int gw = blockIdx.x * 4 + (threadIdx.x >> 6);
  int lane = threadIdx.x & 63;
  if (gw >= B_*KC_) return;
  int b = gw / KC_, k = gw % KC_;
  const float* cr = CNNs + (size_t)(b*KC_ + k)*CC_;
  const float* wr = wij_w + (size_t)k*KX_;
  float acc = 0.f;
  for (int c = lane; c < CC_; c += 64) acc += cr[c] * wr[c];
  const float* sr = s_i + (size_t)b*DH_;
  const float* wsr = wr + CC_;
  #pragma unroll
  for (int j = 0; j < 8; ++j) { int h = lane + j*64; acc += sr[h] * wsr[h]; }
  #pragma unroll
  for (int m = 32; m; m >>= 1) acc += __shfl_xor(acc, m, 64);
  if (lane == 0) ep[gw] = tanhf_fast(acc + wij_b[k]);
}

__global__ void k_cnn_fin(const float* __restrict__ ep, const float* __restrict__ CNNs,
                          float* __restrict__ cp) {
  __shared__ float red[1024];
  __shared__ float apl[B_*KC_];
  int tid = threadIdx.x;
  red[tid] = (tid < B_*KC_) ? ep[tid] : 0.f;
  __syncthreads();
  for (int off = 512; off > 0; off >>= 1) {
    if (tid < off) red[tid] += red[tid + off];
    __syncthreads();
  }
  float S = red[0];
  if (tid < B_*KC_) apl[tid] = __expf(ep[tid]) / S;   // ref: exp(ep)/sum(ep), GLOBAL sum
  __syncthreads();
  for (int idx = tid; idx < B_*CC_; idx += blockDim.x) {
    int b = idx / CC_, c = idx % CC_;
    float acc = 0.f;
    #pragma unroll
    for (int k = 0; k < KC_; ++k)
      acc += apl[b*KC_ + k] * CNNs[(size_t)(b*KC_ + k)*CC_ + c];
    cp[idx] = acc;
  }
}

// ---- Wih fp32 -> bf16 [2048][640], rows reordered nr = dh*4+gate ----
__global__ void k_cvtW(const float* __restrict__ Wih, unsigned short* __restrict__ Wr) {
  int id = blockIdx.x * 256 + threadIdx.x;    // 2048*80
  int nr = id / 80, c8 = (id % 80) * 8;
  int gate = nr & 3, dh = nr >> 2;
  const float* src = Wih + (size_t)(gate*DH_ + dh)*KX_;
  unsigned short o[8];
  #pragma unroll
  for (int j = 0; j < 8; ++j) {
    int col = c8 + j;
    o[j] = (col < KX_) ? f2bf(src[col]) : 0;
  }
  *(uint4*)(Wr + (size_t)nr*KP_ + c8) = *(uint4*)o;
}

// ---- LSTM [b][t][e] fp32 -> LT [b][e][t] bf16 ----
__global__ __launch_bounds__(256) void k_ltrans(const float* __restrict__ LSTM,
                                                unsigned short* __restrict__ LT) {
  int e0 = blockIdx.x * 64, t0 = blockIdx.y * 64, b = blockIdx.z;
  __shared__ float tile[64][65];
  int tid = threadIdx.x;
  int tt = tid >> 2, c16 = (tid & 3) * 16;
  const float4* src = (const float4*)(LSTM + ((size_t)b*TE_ + t0 + tt)*EH_ + e0 + c16);
  float4 v0 = src[0], v1 = src[1], v2 = src[2], v3 = src[3];
  *(float4*)&tile[tt][c16]    = v0;
  *(float4*)&tile[tt][c16+4]  = v1;
  *(float4*)&tile[tt][c16+8]  = v2;
  *(float4*)&tile[tt][c16+12] = v3;
  __syncthreads();
  int e = tid >> 2, t16 = (tid & 3) * 16;
  unsigned short o[16];
  #pragma unroll
  for (int j = 0; j < 16; ++j) o[j] = f2bf(tile[t16+j][e]);
  unsigned short* dst = LT + ((size_t)b*EH_ + e0 + e)*TE_ + t0 + t16;
  *(uint4*)dst     = *(uint4*)&o[0];
  *(uint4*)(dst+8) = *(uint4*)&o[8];
}

// ---------- phase 1: banded logits MFMA band-GEMM (R4 structure) ----------
#define BMM_M 64
#define LDA_  40
#define LDB_  40
__global__ __launch_bounds__(256) void k_bandmm(const float* __restrict__ LSTM,
                                                const float* __restrict__ phi,
                                                const float* __restrict__ Ua_w,
                                                const float* __restrict__ Ua_b,
                                                const float* __restrict__ va_w,
                                                const float* __restrict__ va_b,
                                                const float* __restrict__ wa,
                                                float* __restrict__ ET) {
  int t0 = blockIdx.x * BMM_M;   // 8 tiles
  int b  = blockIdx.y;           // 128
  int s_base = 321 - t0;
  __shared__ short sA[BMM_M * LDA_];
  __shared__ short sB[192 * LDB_];
  int tid = threadIdx.x;
  int wave = tid >> 6, lane = tid & 63;
  int quad = lane >> 4, l16 = lane & 15;

  f32x4 acc[4][3];
  #pragma unroll
  for (int m = 0; m < 4; ++m)
    #pragma unroll
    for (int n = 0; n < 3; ++n)
      acc[m][n] = (f32x4){0.f, 0.f, 0.f, 0.f};

  int arow = tid >> 2;             // 0..63
  int ach  = (tid & 3) * 8;        // shorts
  int aq   = ach >> 2;             // float4 units

  const float4* baseL = (const float4*)(LSTM + ((size_t)b*TE_ + t0 + arow)*EH_);
  const float4* baseP = (const float4*)(phi + (size_t)(t0 + arow)*EH_);
  const float4* baseU[3];
  int brow[3], bch[3];
  #pragma unroll
  for (int c = 0; c < 3; ++c) {
    int idx = c*256 + tid;
    brow[c] = idx >> 2;
    bch[c]  = (idx & 3) * 8;
    int s = s_base + brow[c];
    int sc = s < 0 ? 0 : (s > 511 ? 511 : s);
    baseU[c] = (const float4*)(Ua_w + (size_t)sc*EH_ + bch[c]);
  }

  float4 l0 = baseL[aq], l1 = baseL[aq+1], p0 = baseP[aq], p1 = baseP[aq+1];
  float4 u0[3], u1[3];
  #pragma unroll
  for (int c = 0; c < 3; ++c) { u0[c] = baseU[c][0]; u1[c] = baseU[c][1]; }

  for (int k0 = 0; k0 < EH_; k0 += 32) {
    unsigned short at[8];
    at[0]=f2bf(l0.x*p0.x); at[1]=f2bf(l0.y*p0.y); at[2]=f2bf(l0.z*p0.z); at[3]=f2bf(l0.w*p0.w);
    at[4]=f2bf(l1.x*p1.x); at[5]=f2bf(l1.y*p1.y); at[6]=f2bf(l1.z*p1.z); at[7]=f2bf(l1.w*p1.w);
    unsigned short bt[3][8];
    #pragma unroll
    for (int c = 0; c < 3; ++c) {
      bt[c][0]=f2bf(u0[c].x); bt[c][1]=f2bf(u0[c].y); bt[c][2]=f2bf(u0[c].z); bt[c][3]=f2bf(u0[c].w);
      bt[c][4]=f2bf(u1[c].x); bt[c][5]=f2bf(u1[c].y); bt[c][6]=f2bf(u1[c].z); bt[c][7]=f2bf(u1[c].w);
    }
    if (k0 + 32 < EH_) {                       // prefetch next chunk
      int q = (k0 + 32) >> 2;
      l0 = baseL[q+aq]; l1 = baseL[q+aq+1]; p0 = baseP[q+aq]; p1 = baseP[q+aq+1];
      #pragma unroll
      for (int c = 0; c < 3; ++c) { u0[c] = baseU[c][q]; u1[c] = baseU[c][q+1]; }
    }
    __syncthreads();
    *(uint4*)&sA[arow*LDA_ + ach] = *(uint4*)at;
    #pragma unroll
    for (int c = 0; c < 3; ++c)
      *(uint4*)&sB[brow[c]*LDB_ + bch[c]] = *(uint4*)bt[c];
    __syncthreads();
    bf16x8 bfr[3];
    #pragma unroll
    for (int n = 0; n < 3; ++n)
      bfr[n] = *(const bf16x8*)&sB[(l16 + (wave*3 + n)*16)*LDB_ + quad*8];
    #pragma unroll
    for (int m = 0; m < 4; ++m) {
      bf16x8 af = *(const bf16x8*)&sA[(l16 + m*16)*LDA_ + quad*8];
      #pragma unroll
      for (int n = 0; n < 3; ++n)
        acc[m][n] = __builtin_amdgcn_mfma_f32_16x16x32_bf16(af, bfr[n], acc[m][n], 0, 0, 0);
    }
  }

  float vb = va_b[0];
  #pragma unroll
  for (int n = 0; n < 3; ++n) {
    int s = s_base + wave*48 + n*16 + l16;
    float ub = (s >= 0 && s < TE_) ? Ua_b[s] : 0.f;
    float vw = (s >= 0 && s < TE_) ? va_w[TD_ + s] : 0.f;
    #pragma unroll
    for (int m = 0; m < 4; ++m) {
      #pragma unroll
      for (int r = 0; r < 4; ++r) {
        int t = t0 + m*16 + quad*4 + r;
        int i = s + t - 384;
        if (i >= 0 && i < TD_) {
          float val;
          if (s >= 0) val = tanhf_fast(acc[m][n][r] + ub) * vw + vb;
          else        val = wa[b*TD_ + s + 128] + vb;
          ET[((size_t)b*TE_ + t)*TD_ + i] = val;
        }
      }
    }
  }
}

// ---------------- phase 2: softmax stats over t ----------------
__global__ __launch_bounds__(256) void k_stats(const float* __restrict__ ET,
                                               float* __restrict__ stat) {
  int i0 = blockIdx.x * 64, b = blockIdx.y;
  __shared__ float red[4][64], smax[64];
  int tid = threadIdx.x;
  int q = tid >> 6, il = tid & 63;
  const float* col = ET + (size_t)b*TE_*TD_ + i0 + il;
  float m = -1e30f;
  for (int t = q*128; t < q*128 + 128; ++t) m = fmaxf(m, col[(size_t)t*TD_]);
  red[q][il] = m;
  __syncthreads();
  if (tid < 64) {
    float mm = fmaxf(fmaxf(red[0][tid], red[1][tid]), fmaxf(red[2][tid], red[3][tid]));
    smax[tid] = mm;
  }
  __syncthreads();
  float mm = smax[il];
  float s = 0.f;
  for (int t = q*128; t < q*128 + 128; ++t) s += __expf(col[(size_t)t*TD_] - mm);
  __syncthreads();
  red[q][il] = s;
  __syncthreads();
  if (tid < 64) {
    float ss = red[0][tid] + red[1][tid] + red[2][tid] + red[3][tid];
    stat[b*TD_ + i0 + tid] = smax[tid];
    stat[(size_t)B_*TD_ + b*TD_ + i0 + tid] = 1.f/ss;
  }
}

// ---- ET [b][t][i] + stats -> P [b][i][t] bf16 (softmax applied, transposed) ----
__global__ __launch_bounds__(256) void k_trP(const float* __restrict__ ET,
                                             const float* __restrict__ stat,
                                             unsigned short* __restrict__ P) {
  int t0 = blockIdx.x * 64, i0 = blockIdx.y * 64, b = blockIdx.z;
  __shared__ float tile[64][65];
  __shared__ float smL[64], svL[64];
  int tid = threadIdx.x;
  if (tid < 64) {
    smL[tid] = stat[b*TD_ + i0 + tid];
    svL[tid] = stat[(size_t)B_*TD_ + b*TD_ + i0 + tid];
  }
  int tt = tid >> 2, c16 = (tid & 3) * 16;
  const float4* src = (const float4*)(ET + ((size_t)b*TE_ + t0 + tt)*TD_ + i0 + c16);
  float4 v[4]; v[0] = src[0]; v[1] = src[1]; v[2] = src[2]; v[3] = src[3];
  __syncthreads();
  const float* vf = (const float*)v;
  #pragma unroll
  for (int j = 0; j < 16; ++j)
    tile[tt][c16+j] = __expf(vf[j] - smL[c16+j]) * svL[c16+j];
  __syncthreads();
  int i = tid >> 2, t16 = (tid & 3) * 16;
  unsigned short o[16];
  #pragma unroll
  for (int j = 0; j < 16; ++j) o[j] = f2bf(tile[t16+j][i]);
  unsigned short* dst = P + ((size_t)b*TD_ + i0 + i)*TE_ + t0 + t16;
  *(uint4*)dst     = *(uint4*)&o[0];
  *(uint4*)(dst+8) = *(uint4*)&o[8];
}

// ---- fill X[:,512:640] from cp (bf16), zero pad ----
__global__ void k_cp_fill(const float* __restrict__ cp, unsigned short* __restrict__ X) {
  int id = blockIdx.x * 256 + threadIdx.x;  // 16384*16
  int m = id >> 4, c8 = (id & 15) * 8;
  int b = m >> 7;
  unsigned short o[8];
  #pragma unroll
  for (int j = 0; j < 8; ++j) {
    int c = c8 + j;
    o[j] = (c < CC_) ? f2bf(cp[b*CC_ + c]) : 0;
  }
  *(uint4*)(X + (size_t)m*KP_ + EH_ + c8) = *(uint4*)o;
}

// ------ phase 3 (MFMA, BK=32): X[b*128+i][e] = sum_t P[b][i][t]*LT[b][e][t] ------
#define CI_LD 40
__global__ __launch_bounds__(256) void k_ci_mm(const unsigned short* __restrict__ P,
                                               const unsigned short* __restrict__ LT,
                                               unsigned short* __restrict__ X) {
  int b = blockIdx.x, e0 = blockIdx.y * 128;
  __shared__ short sA[128 * CI_LD];
  __shared__ short sB[128 * CI_LD];
  int tid = threadIdx.x;
  int wave = tid >> 6, lane = tid & 63, quad = lane >> 4, l16 = lane & 15;
  int wm = wave >> 1, wn = wave & 1;
  int row = tid >> 1, ho = (tid & 1) * 16;

  const unsigned short* pa = P + ((size_t)b*TD_ + row)*TE_ + ho;
  const unsigned short* pb = LT + ((size_t)b*EH_ + e0 + row)*TE_ + ho;

  f32x4 acc[4][4];
  #pragma unroll
  for (int m = 0; m < 4; ++m)
    #pragma unroll
    for (int n = 0; n < 4; ++n)
      acc[m][n] = (f32x4){0.f, 0.f, 0.f, 0.f};

  uint4 a0 = *(const uint4*)pa, a1 = *(const uint4*)(pa + 8);
  uint4 b0 = *(const uint4*)pb, b1 = *(const uint4*)(pb + 8);

  for (int k0 = 0; k0 < TE_; k0 += 32) {
    uint4 na0, na1, nb0, nb1;
    if (k0 + 32 < TE_) {
      na0 = *(const uint4*)(pa + k0 + 32); na1 = *(const uint4*)(pa + k0 + 40);
      nb0 = *(const uint4*)(pb + k0 + 32); nb1 = *(const uint4*)(pb + k0 + 40);
    }
    __syncthreads();
    *(uint4*)&sA[row*CI_LD + ho]     = a0;
    *(uint4*)&sA[row*CI_LD + ho + 8] = a1;
    *(uint4*)&sB[row*CI_LD + ho]     = b0;
    *(uint4*)&sB[row*CI_LD + ho + 8] = b1;
    __syncthreads();
    bf16x8 bfr[4];
    #pragma unroll
    for (int n = 0; n < 4; ++n)
      bfr[n] = *(const bf16x8*)&sB[(wn*64 + n*16 + l16)*CI_LD + quad*8];
    #pragma unroll
    for (int m = 0; m < 4; ++m) {
      bf16x8 af = *(const bf16x8*)&sA[(wm*64 + m*16 + l16)*CI_LD + quad*8];
      #pragma unroll
      for (int n = 0; n < 4; ++n)
        acc[m][n] = __builtin_amdgcn_mfma_f32_16x16x32_bf16(af, bfr[n], acc[m][n], 0, 0, 0);
    }
    a0 = na0; a1 = na1; b0 = nb0; b1 = nb1;
  }

  #pragma unroll
  for (int m = 0; m < 4; ++m) {
    int i = wm*64 + m*16 + quad*4;
    #pragma unroll
    for (int n = 0; n < 4; ++n) {
      int e = e0 + wn*64 + n*16 + l16;
      unsigned short* xp = X + ((size_t)b*TD_ + i)*KP_ + e;
      #pragma unroll
      for (int r = 0; r < 4; ++r)
        xp[(size_t)r*KP_] = f2bf(acc[m][n][r]);
    }
  }
}

// -- phase 4 (MFMA, BK=32): gates = X @ Wr^T + fused LSTM cell --
__global__ __launch_bounds__(256) void k_gates_mm(const unsigned short* __restrict__ Wr,
                                                  const unsigned short* __restrict__ X,
                                                  const float* __restrict__ hpre,
                                                  const float* __restrict__ m_i,
                                                  float* __restrict__ out) {
  int g0 = blockIdx.x * 128;
  int mi0 = blockIdx.y * 128;
  __shared__ short sA[128 * CI_LD];
  __shared__ short sB[128 * CI_LD];
  int tid = threadIdx.x;
  int wave = tid >> 6, lane = tid & 63, quad = lane >> 4, l16 = lane & 15;
  int wg = wave >> 1, wmi = wave & 1;
  int row = tid >> 1, ho = (tid & 1) * 16;

  const unsigned short* pa = Wr + (size_t)(g0 + row)*KP_ + ho;
  const unsigned short* pb = X + (size_t)(mi0 + row)*KP_ + ho;

  f32x4 acc[4][4];
  #pragma unroll
  for (int m = 0; m < 4; ++m)
    #pragma unroll
    for (int n = 0; n < 4; ++n)
      acc[m][n] = (f32x4){0.f, 0.f, 0.f, 0.f};

  uint4 a0 = *(const uint4*)pa, a1 = *(const uint4*)(pa + 8);
  uint4 b0 = *(const uint4*)pb, b1 = *(const uint4*)(pb + 8);

  for (int k0 = 0; k0 < KP_; k0 += 32) {
    uint4 na0, na1, nb0, nb1;
    if (k0 + 32 < KP_) {
      na0 = *(const uint4*)(pa + k0 + 32); na1 = *(const uint4*)(pa + k0 + 40);
      nb0 = *(const uint4*)(pb + k0 + 32); nb1 = *(const uint4*)(pb + k0 + 40);
    }
    __syncthreads();
    *(uint4*)&sA[row*CI_LD + ho]     = a0;
    *(uint4*)&sA[row*CI_LD + ho + 8] = a1;
    *(uint4*)&sB[row*CI_LD + ho]     = b0;
    *(uint4*)&sB[row*CI_LD + ho + 8] = b1;
    __syncthreads();
    bf16x8 bfr[4];
    #pragma unroll
    for (int n = 0; n < 4; ++n)
      bfr[n] = *(const bf16x8*)&sB[(wmi*64 + n*16 + l16)*CI_LD + quad*8];
    #pragma unroll
    for (int m = 0; m < 4; ++m) {
      bf16x8 af = *(const bf16x8*)&sA[(wg*64 + m*16 + l16)*CI_LD + quad*8];
      #pragma unroll
      for (int n = 0; n < 4; ++n)
        acc[m][n] = __builtin_amdgcn_mfma_f32_16x16x32_bf16(af, bfr[n], acc[m][n], 0, 0, 0);
    }
    a0 = na0; a1 = na1; b0 = nb0; b1 = nb1;
  }

  // lane regs r=0..3 are (ig,fg,gg,og) of dh; b is block-uniform
  int bbk = mi0 >> 7;
  const float* hp = hpre + (size_t)bbk*G_;
  #pragma unroll
  for (int m = 0; m < 4; ++m) {
    int dh = (g0 >> 2) + wg*16 + m*4 + quad;
    float h0 = hp[dh], h1 = hp[DH_ + dh], h2 = hp[2*DH_ + dh], h3 = hp[3*DH_ + dh];
    float miv = m_i[(size_t)bbk*DH_ + dh];
    #pragma unroll
    for (int n = 0; n < 4; ++n) {
      int mi = mi0 + wmi*64 + n*16 + l16;
      float ig = acc[m][n][0] + h0;
      float fg = acc[m][n][1] + h1;
      float gg = acc[m][n][2] + h2;
      float og = acc[m][n][3] + h3;
      float c  = sigm(fg)*miv + sigm(ig)*tanhf_fast(gg);
      float h  = sigm(og)*tanhf_fast(c);
      out[(size_t)mi*DH_ + dh] = h;
    }
  }
}

extern "C" void kernel_launch(void* const* d_in, const int* in_sizes, int n_in,
                              void* d_out, int out_size, void* d_ws, size_t ws_size,
                              hipStream_t stream) {
  (void)in_sizes; (void)n_in; (void)out_size; (void)ws_size;
  const float* LSTM  = (const float*)d_in[0];
  const float* CNNs  = (const float*)d_in[1];
  const float* Wa_w  = (const float*)d_in[2];
  const float* Wa_b  = (const float*)d_in[3];
  const float* Ua_w  = (const float*)d_in[4];
  const float* Ua_b  = (const float*)d_in[5];
  const float* va_w  = (const float*)d_in[6];
  const float* va_b  = (const float*)d_in[7];
  const float* phi_w = (const float*)d_in[8];
  const float* phi_b = (const float*)d_in[9];
  const float* Wih   = (const float*)d_in[10];
  const float* Whh   = (const float*)d_in[11];
  const float* bih   = (const float*)d_in[12];
  const float* bhh   = (const float*)d_in[13];
  const float* wij_w = (const float*)d_in[14];
  const float* wij_b = (const float*)d_in[15];
  const float* s_i   = (const float*)d_in[16];
  const float* m_i   = (const float*)d_in[17];
  float* out = (float*)d_out;
  char* ws = (char*)d_ws;

  float* phi  = (float*)(ws + OFF_PHI);
  float* wa   = (float*)(ws + OFF_WA);
  float* hpre = (float*)(ws + OFF_HPRE);
  float* ep   = (float*)(ws + OFF_EP);
  float* cp   = (float*)(ws + OFF_CP);
  float* stat = (float*)(ws + OFF_STAT);
  float* ET   = (float*)(ws + OFF_ET);
  unsigned short* X  = (unsigned short*)(ws + OFF_ET);   // aliases ET (dead after k_trP)
  unsigned short* P  = (unsigned short*)(ws + OFF_P);
  unsigned short* LT = (unsigned short*)(ws + OFF_LT);
  unsigned short* Wr = (unsigned short*)(ws + OFF_WR);
  float* phiT        = (float*)(ws + OFF_PT);            // aliases P region (pre-trP)
  float* sums        = (float*)(ws + OFF_SUM);           // aliases P region

  k_trw     <<<dim3(8,8),      dim3(256),  0, stream>>>(phi_w, phiT);
  k_phiA    <<<dim3(2,8),      dim3(256),  0, stream>>>(phiT, phi, sums);
  k_phiB    <<<dim3(2,8),      dim3(256),  0, stream>>>(sums, phi_b, phi);
  k_wa      <<<dim3(64),       dim3(256),  0, stream>>>(s_i, Wa_w, Wa_b, va_w, wa);
  k_hpre    <<<dim3(1024),     dim3(256),  0, stream>>>(s_i, Whh, bih, bhh, hpre);
  k_ep      <<<dim3(224),      dim3(256),  0, stream>>>(CNNs, wij_w, wij_b, s_i, ep);
  k_cnn_fin <<<dim3(1),        dim3(1024), 0, stream>>>(ep, CNNs, cp);
  k_cvtW    <<<dim3(640),      dim3(256),  0, stream>>>(Wih, Wr);
  k_ltrans  <<<dim3(8,8,128),  dim3(256),  0, stream>>>(LSTM, LT);
  k_bandmm  <<<dim3(8,128),    dim3(256),  0, stream>>>(LSTM, phi, Ua_w, Ua_b, va_w, va_b, wa, ET);
  k_stats   <<<dim3(2,128),    dim3(256),  0, stream>>>(ET, stat);
  k_trP     <<<dim3(8,2,128),  dim3(256),  0, stream>>>(ET, stat, P);
  k_cp_fill <<<dim3(1024),     dim3(256),  0, stream>>>(cp, X);
  k_ci_mm   <<<dim3(128,4),    dim3(256),  0, stream>>>(P, LT, X);
  k_gates_mm<<<dim3(16,128),   dim3(256),  0, stream>>>(Wr, X, hpre, m_i, out);
}